// Round 2
// baseline (248.103 us; speedup 1.0000x reference)
//
#include <hip/hip_runtime.h>
#include <hip/hip_bf16.h>
#include <math.h>

#define VOCAB 100000
#define EMB 100
#define HID 100
#define CTX_LEN 60
#define FACT_LEN 20
#define DESC_LEN 60
#define NCHUNK (VOCAB / 16)   // 6250 column chunks of 16

// workspace layout (float offsets)
#define WS_FACTS 0        // 6000
#define WS_X     6000     // 6000
#define WS_H0    12000    // 128
#define WS_GI    12160    // 18000 (60 x 300)
#define WS_H     30160    // 6000  (60 x 100)
#define WS_MS    36864    // float2[60][nwaves]

typedef __attribute__((ext_vector_type(8))) short short8;
typedef __attribute__((ext_vector_type(4))) float f32x4;

static __device__ __forceinline__ unsigned short f2bf(float f) {
    union { float f; unsigned u; } x; x.f = f;
    unsigned r = (x.u + 0x7FFFu + ((x.u >> 16) & 1u)) >> 16;
    return (unsigned short)r;
}

// ---------------- K1: facts encoder + decoder input embeddings + zero d_out ----------------
__global__ __launch_bounds__(128) void k1_prep(const int* __restrict__ context,
                                               const int* __restrict__ desc,
                                               const float* __restrict__ emb_ctx,
                                               const float* __restrict__ emb_dec,
                                               float* __restrict__ ws,
                                               float* __restrict__ out) {
    int b = blockIdx.x, tid = threadIdx.x;
    if (b < 60) {
        __shared__ int toks[20];
        if (tid < 20) toks[tid] = context[b * 20 + tid];
        __syncthreads();
        if (tid < 100) {
            float ef = tid * (1.f / 99.f);
            float acc = 0.f;
            #pragma unroll
            for (int s = 0; s < 20; s++) {
                float sf = s * (1.f / 19.f);
                float l = 1.f - sf - ef * (1.f - 2.f * sf);
                acc = fmaf(emb_ctx[toks[s] * 100 + tid], l, acc);
            }
            ws[WS_FACTS + b * 100 + tid] = acc;
        }
    } else {
        int t = b - 60;
        int tok = (t == 0) ? 1 : desc[t - 1];
        if (tid < 100) ws[WS_X + t * 100 + tid] = emb_dec[tok * 100 + tid];
        if (b == 60 && tid == 0) out[0] = 0.f;   // d_out is poisoned; K5 atomicAdds into it
    }
}

// ---------------- K2: h0 (blocks 0..99) + gi_all (blocks 100..159) ----------------
__global__ __launch_bounds__(320) void k2_h0_gi(const float* __restrict__ w1,
                                                const float* __restrict__ b1,
                                                const float* __restrict__ w_ih,
                                                const float* __restrict__ b_ih,
                                                float* __restrict__ ws) {
    int b = blockIdx.x, tid = threadIdx.x;
    if (b < 100) {
        __shared__ float red[320];
        const float* facts = ws + WS_FACTS;
        const float* wr = w1 + b * 6000;
        float p = 0.f;
        for (int k = tid; k < 6000; k += 320) p = fmaf(facts[k], wr[k], p);
        red[tid] = p; __syncthreads();
        if (tid < 64) red[tid] += red[256 + tid];
        __syncthreads();
        for (int st = 128; st > 0; st >>= 1) {
            if (tid < st) red[tid] += red[tid + st];
            __syncthreads();
        }
        if (tid == 0) ws[WS_H0 + b] = red[0] + b1[b];
    } else {
        int t = b - 100;
        __shared__ float xs[100];
        if (tid < 100) xs[tid] = ws[WS_X + t * 100 + tid];
        __syncthreads();
        if (tid < 300) {
            float p = b_ih[tid];
            const float* wr = w_ih + tid * 100;
            #pragma unroll 4
            for (int k = 0; k < 100; k++) p = fmaf(wr[k], xs[k], p);
            ws[WS_GI + t * 300 + tid] = p;
        }
    }
}

// ---------------- K3: sequential GRU (single block; w_hh TRULY register-resident) ----------------
// __launch_bounds__(320, 1): min 1 wave/EU lifts the VGPR cap so wreg[100] does
// NOT spill to scratch (round-1: VGPR_Count=64 -> spill -> 64us L2-bound).
__global__ __launch_bounds__(320, 1) void k3_gru(const float* __restrict__ w_hh,
                                                 const float* __restrict__ b_hh,
                                                 float* __restrict__ ws) {
    __shared__ __align__(16) float h_lds[128];
    __shared__ float gh_lds[304];
    const int j = threadIdx.x;
    float wreg[100];
    float bhh = 0.f;
    if (j < 300) {
        bhh = b_hh[j];
        #pragma unroll
        for (int k4 = 0; k4 < 25; k4++) {
            float4 v = *(const float4*)(w_hh + j * 100 + k4 * 4);
            wreg[k4 * 4 + 0] = v.x; wreg[k4 * 4 + 1] = v.y;
            wreg[k4 * 4 + 2] = v.z; wreg[k4 * 4 + 3] = v.w;
        }
    }
    float hreg = 0.f;
    if (j < 100) { hreg = ws[WS_H0 + j]; h_lds[j] = hreg; }
    __syncthreads();

    const float* gi = ws + WS_GI;
    float* H = ws + WS_H;
    for (int t = 0; t < 60; t++) {
        if (j < 300) {
            // 4 independent accumulators: dep chain 100 -> 25 fma deps
            float a0 = bhh, a1 = 0.f, a2 = 0.f, a3 = 0.f;
            #pragma unroll
            for (int k4 = 0; k4 < 25; k4++) {
                float4 hv = *(const float4*)(h_lds + k4 * 4);  // broadcast, conflict-free
                a0 = fmaf(wreg[k4 * 4 + 0], hv.x, a0);
                a1 = fmaf(wreg[k4 * 4 + 1], hv.y, a1);
                a2 = fmaf(wreg[k4 * 4 + 2], hv.z, a2);
                a3 = fmaf(wreg[k4 * 4 + 3], hv.w, a3);
            }
            gh_lds[j] = (a0 + a1) + (a2 + a3);
        }
        __syncthreads();
        if (j < 100) {
            float gir = gi[t * 300 + j];
            float giz = gi[t * 300 + 100 + j];
            float gin = gi[t * 300 + 200 + j];
            float ghr = gh_lds[j], ghz = gh_lds[100 + j], ghn = gh_lds[200 + j];
            float r = 1.f / (1.f + __expf(-(gir + ghr)));
            float z = 1.f / (1.f + __expf(-(giz + ghz)));
            float a = fmaf(r, ghn, gin);
            // tanh via expf, sign-safe
            float tt = __expf(-2.f * fabsf(a));
            float n = copysignf((1.f - tt) / (1.f + tt), a);
            hreg = (1.f - z) * n + z * hreg;
            h_lds[j] = hreg;
            H[t * 100 + j] = hreg;
        }
        __syncthreads();
    }
}

// ---------------- K4: logits GEMM (bf16 MFMA) + online softmax partials ----------------
__global__ __launch_bounds__(256, 1) void k4_logits(const float* __restrict__ w_out,
                                                    const float* __restrict__ b_out,
                                                    float* __restrict__ ws,
                                                    int nwaves) {
    const float* H = ws + WS_H;
    float* ms = ws + WS_MS;
    const int lane = threadIdx.x & 63;
    const int gw = blockIdx.x * 4 + (threadIdx.x >> 6);
    const int q = lane >> 4, n = lane & 15;
    const int k_base = q * 8;

    // A fragments: H rows (t), zero-padded to 64 x 128, float4 loads
    short8 afr[4][4];
    #pragma unroll
    for (int mt = 0; mt < 4; mt++) {
        int m = mt * 16 + n;
        #pragma unroll
        for (int kt = 0; kt < 4; kt++) {
            int k0 = kt * 32 + k_base;
            float va[8];
            #pragma unroll
            for (int jj = 0; jj < 8; jj++) va[jj] = 0.f;
            if (m < 60) {
                if (k0 + 4 <= 100) {
                    float4 a = *(const float4*)(H + m * 100 + k0);
                    va[0] = a.x; va[1] = a.y; va[2] = a.z; va[3] = a.w;
                }
                if (k0 + 8 <= 100) {
                    float4 b = *(const float4*)(H + m * 100 + k0 + 4);
                    va[4] = b.x; va[5] = b.y; va[6] = b.z; va[7] = b.w;
                }
            }
            short8 f;
            #pragma unroll
            for (int jj = 0; jj < 8; jj++) f[jj] = (short)f2bf(va[jj]);
            afr[mt][kt] = f;
        }
    }

    float mS[16], sS[16];
    #pragma unroll
    for (int i = 0; i < 16; i++) { mS[i] = -3.0e38f; sS[i] = 0.f; }

    for (int c = gw; c < NCHUNK; c += nwaves) {
        int row = c * 16 + n;
        short8 bfr[4];
        #pragma unroll
        for (int kt = 0; kt < 4; kt++) {
            int k0 = kt * 32 + k_base;
            float va[8];
            #pragma unroll
            for (int jj = 0; jj < 8; jj++) va[jj] = 0.f;
            if (k0 + 4 <= 100) {
                float4 a = *(const float4*)(w_out + row * 100 + k0);
                va[0] = a.x; va[1] = a.y; va[2] = a.z; va[3] = a.w;
            }
            if (k0 + 8 <= 100) {
                float4 b = *(const float4*)(w_out + row * 100 + k0 + 4);
                va[4] = b.x; va[5] = b.y; va[6] = b.z; va[7] = b.w;
            }
            short8 f;
            #pragma unroll
            for (int jj = 0; jj < 8; jj++) f[jj] = (short)f2bf(va[jj]);
            bfr[kt] = f;
        }
        float bo = b_out[row];
        #pragma unroll
        for (int mt = 0; mt < 4; mt++) {
            f32x4 acc = {0.f, 0.f, 0.f, 0.f};
            acc = __builtin_amdgcn_mfma_f32_16x16x32_bf16(afr[mt][0], bfr[0], acc, 0, 0, 0);
            acc = __builtin_amdgcn_mfma_f32_16x16x32_bf16(afr[mt][1], bfr[1], acc, 0, 0, 0);
            acc = __builtin_amdgcn_mfma_f32_16x16x32_bf16(afr[mt][2], bfr[2], acc, 0, 0, 0);
            acc = __builtin_amdgcn_mfma_f32_16x16x32_bf16(afr[mt][3], bfr[3], acc, 0, 0, 0);
            #pragma unroll
            for (int reg = 0; reg < 4; reg++) {
                float x = acc[reg] + bo;            // logit for (t = mt*16+q*4+reg, v = row)
                int i = mt * 4 + reg;
                float mo = mS[i];
                float mn = fmaxf(mo, x);
                sS[i] = sS[i] * __expf(mo - mn) + __expf(x - mn);
                mS[i] = mn;
            }
        }
    }

    // reduce (m,s) across the 16 column lanes
    #pragma unroll
    for (int i = 0; i < 16; i++) {
        float m = mS[i], s = sS[i];
        #pragma unroll
        for (int off = 1; off < 16; off <<= 1) {
            float m2 = __shfl_xor(m, off);
            float s2 = __shfl_xor(s, off);
            float mn = fmaxf(m, m2);
            s = s * __expf(m - mn) + s2 * __expf(m2 - mn);
            m = mn;
        }
        mS[i] = m; sS[i] = s;
    }
    if (n == 0) {
        #pragma unroll
        for (int mt = 0; mt < 4; mt++) {
            #pragma unroll
            for (int reg = 0; reg < 4; reg++) {
                int t = mt * 16 + q * 4 + reg;
                int i = mt * 4 + reg;
                if (t < 60) {
                    float2 val; val.x = mS[i]; val.y = sS[i];
                    ((float2*)ms)[t * nwaves + gw] = val;
                }
            }
        }
    }
}

// ---------------- K5: combine partials per t, add -logit[tok], accumulate loss ----------------
__global__ __launch_bounds__(256) void k5_final(const int* __restrict__ desc,
                                                const float* __restrict__ w_out,
                                                const float* __restrict__ b_out,
                                                const float* __restrict__ ws,
                                                float* __restrict__ out,
                                                int nwaves) {
    int t = blockIdx.x, tid = threadIdx.x;
    __shared__ float sm[256], ss[256], sd[256];
    const float2* ms = (const float2*)(ws + WS_MS);
    float m = -3.0e38f, s = 0.f;
    for (int i = tid; i < nwaves; i += 256) {
        float2 p = ms[t * nwaves + i];
        float mn = fmaxf(m, p.x);
        s = s * __expf(m - mn) + p.y * __expf(p.x - mn);
        m = mn;
    }
    sm[tid] = m; ss[tid] = s; __syncthreads();
    for (int st = 128; st > 0; st >>= 1) {
        if (tid < st) {
            float mo = sm[tid], so = ss[tid];
            float m2 = sm[tid + st], s2 = ss[tid + st];
            float mn = fmaxf(mo, m2);
            sm[tid] = mn;
            ss[tid] = so * __expf(mo - mn) + s2 * __expf(m2 - mn);
        }
        __syncthreads();
    }
    int tok = desc[t];
    float p = 0.f;
    if (tid < 100) p = ws[WS_H + t * 100 + tid] * w_out[tok * 100 + tid];
    sd[tid] = p; __syncthreads();
    for (int st = 128; st > 0; st >>= 1) {
        if (tid < st) sd[tid] += sd[tid + st];
        __syncthreads();
    }
    if (tid == 0) {
        float logit = sd[0] + b_out[tok];
        float loss = sm[0] + logf(ss[0]) - logit;
        atomicAdd(out, loss);
    }
}

extern "C" void kernel_launch(void* const* d_in, const int* in_sizes, int n_in,
                              void* d_out, int out_size, void* d_ws, size_t ws_size,
                              hipStream_t stream) {
    const int*   context = (const int*)d_in[0];
    // d_in[1] = fact_lengths (unused by reference)
    const int*   desc    = (const int*)d_in[2];
    const float* emb_ctx = (const float*)d_in[3];
    const float* emb_dec = (const float*)d_in[4];
    const float* w1      = (const float*)d_in[5];
    const float* b1      = (const float*)d_in[6];
    const float* w_ih    = (const float*)d_in[7];
    const float* w_hh    = (const float*)d_in[8];
    const float* b_ih    = (const float*)d_in[9];
    const float* b_hh    = (const float*)d_in[10];
    const float* w_out   = (const float*)d_in[11];
    const float* b_out   = (const float*)d_in[12];
    float* out = (float*)d_out;
    float* ws  = (float*)d_ws;

    // 512 blocks -> 2 blocks/CU, 2048 waves (needs ~1.13 MB ws); fall back to 256.
    int nblocks = 512;
    size_t need = (size_t)(WS_MS + 60 * (nblocks * 4) * 2) * 4;
    if (ws_size < need) nblocks = 256;
    int nwaves = nblocks * 4;

    k1_prep  <<<120, 128, 0, stream>>>(context, desc, emb_ctx, emb_dec, ws, out);
    k2_h0_gi <<<160, 320, 0, stream>>>(w1, b1, w_ih, b_ih, ws);
    k3_gru   <<<1,   320, 0, stream>>>(w_hh, b_hh, ws);
    k4_logits<<<nblocks, 256, 0, stream>>>(w_out, b_out, ws, nwaves);
    k5_final <<<60,  256, 0, stream>>>(desc, w_out, b_out, ws, out, nwaves);
}

// Round 3
// 204.050 us; speedup vs baseline: 1.2159x; 1.2159x over previous
//
#include <hip/hip_runtime.h>
#include <hip/hip_bf16.h>
#include <math.h>

#define VOCAB 100000
#define EMB 100
#define HID 100
#define CTX_LEN 60
#define FACT_LEN 20
#define DESC_LEN 60
#define NCHUNK (VOCAB / 16)   // 6250 column chunks of 16
#define NWAVES 1024

// workspace layout (float offsets)
#define WS_FACTS 0        // 6000
#define WS_X     6000     // 6000
#define WS_H0    12000    // 128
#define WS_GI    12160    // 18000 (60 x 300)
#define WS_H     30160    // 6000  (60 x 100)
#define WS_MS    36864    // float2[60][NWAVES]

typedef __attribute__((ext_vector_type(8))) short short8;
typedef __attribute__((ext_vector_type(4))) float f32x4;

static __device__ __forceinline__ unsigned short f2bf(float f) {
    union { float f; unsigned u; } x; x.f = f;
    unsigned r = (x.u + 0x7FFFu + ((x.u >> 16) & 1u)) >> 16;
    return (unsigned short)r;
}

// ---------------- K1: facts encoder + decoder input embeddings + zero d_out ----------------
__global__ __launch_bounds__(128) void k1_prep(const int* __restrict__ context,
                                               const int* __restrict__ desc,
                                               const float* __restrict__ emb_ctx,
                                               const float* __restrict__ emb_dec,
                                               float* __restrict__ ws,
                                               float* __restrict__ out) {
    int b = blockIdx.x, tid = threadIdx.x;
    if (b < 60) {
        __shared__ int toks[20];
        if (tid < 20) toks[tid] = context[b * 20 + tid];
        __syncthreads();
        if (tid < 100) {
            float ef = tid * (1.f / 99.f);
            float acc = 0.f;
            #pragma unroll
            for (int s = 0; s < 20; s++) {
                float sf = s * (1.f / 19.f);
                float l = 1.f - sf - ef * (1.f - 2.f * sf);
                acc = fmaf(emb_ctx[toks[s] * 100 + tid], l, acc);
            }
            ws[WS_FACTS + b * 100 + tid] = acc;
        }
    } else {
        int t = b - 60;
        int tok = (t == 0) ? 1 : desc[t - 1];
        if (tid < 100) ws[WS_X + t * 100 + tid] = emb_dec[tok * 100 + tid];
        if (b == 60 && tid == 0) out[0] = 0.f;   // d_out is poisoned; K5 atomicAdds into it
    }
}

// ---------------- K2: h0 (blocks 0..99) + gi_all (blocks 100..159) ----------------
__global__ __launch_bounds__(320) void k2_h0_gi(const float* __restrict__ w1,
                                                const float* __restrict__ b1,
                                                const float* __restrict__ w_ih,
                                                const float* __restrict__ b_ih,
                                                float* __restrict__ ws) {
    int b = blockIdx.x, tid = threadIdx.x;
    if (b < 100) {
        __shared__ float red[320];
        const float* facts = ws + WS_FACTS;
        const float* wr = w1 + b * 6000;
        float p = 0.f;
        for (int k = tid; k < 6000; k += 320) p = fmaf(facts[k], wr[k], p);
        red[tid] = p; __syncthreads();
        if (tid < 64) red[tid] += red[256 + tid];
        __syncthreads();
        for (int st = 128; st > 0; st >>= 1) {
            if (tid < st) red[tid] += red[tid + st];
            __syncthreads();
        }
        if (tid == 0) ws[WS_H0 + b] = red[0] + b1[b];
    } else {
        int t = b - 100;
        __shared__ float xs[100];
        if (tid < 100) xs[tid] = ws[WS_X + t * 100 + tid];
        __syncthreads();
        if (tid < 300) {
            float p = b_ih[tid];
            const float* wr = w_ih + tid * 100;
            #pragma unroll 4
            for (int k = 0; k < 100; k++) p = fmaf(wr[k], xs[k], p);
            ws[WS_GI + t * 300 + tid] = p;
        }
    }
}

// ---------------- K3: sequential GRU via MFMA ----------------
// gh = W_hh(300x100) @ h: h replicated across the 16 M-rows of a 16x16x32 bf16
// MFMA -> every D row equals gh for 16 output columns. Weights live as 16
// short8 B-fragments (64 VGPRs, vector-typed, no scalar-array spill). h is
// bf16 in LDS: one ds_read_b128 per k-tile per wave (vs 25 b128/THREAD before).
// gi preloaded to LDS (72 KB) so the serial loop never touches global reads.
__global__ __launch_bounds__(320, 1) void k3_gru(const float* __restrict__ w_hh,
                                                 const float* __restrict__ b_hh,
                                                 float* __restrict__ ws) {
    __shared__ float gi_lds[18000];
    __shared__ float gh_lds[320];
    __shared__ __align__(16) unsigned short h_bf[128];

    const int tid = threadIdx.x;
    const int wave = tid >> 6, lane = tid & 63;
    const int q = lane >> 4, n = lane & 15;

    // B-fragments: bfr[i*4+kt] holds w_hh[(wave*4+i)*16+n][kt*32+q*8 .. +8) as bf16
    short8 bfr[16];
    #pragma unroll
    for (int i = 0; i < 4; i++) {
        int row = (wave * 4 + i) * 16 + n;
        const float* wr = w_hh + row * 100;
        #pragma unroll
        for (int kt = 0; kt < 4; kt++) {
            int k0 = kt * 32 + q * 8;
            float va[8];
            #pragma unroll
            for (int jj = 0; jj < 8; jj++) va[jj] = 0.f;
            if (row < 300) {
                if (k0 + 4 <= 100) {
                    float4 a = *(const float4*)(wr + k0);
                    va[0] = a.x; va[1] = a.y; va[2] = a.z; va[3] = a.w;
                }
                if (k0 + 8 <= 100) {
                    float4 b = *(const float4*)(wr + k0 + 4);
                    va[4] = b.x; va[5] = b.y; va[6] = b.z; va[7] = b.w;
                }
            }
            short8 f;
            #pragma unroll
            for (int jj = 0; jj < 8; jj++) f[jj] = (short)f2bf(va[jj]);
            bfr[i * 4 + kt] = f;
        }
    }

    // preload gi (60x300) into LDS
    for (int k = tid; k < 18000; k += 320) gi_lds[k] = ws[WS_GI + k];

    // init h
    float hreg = 0.f, bh0 = 0.f, bh1 = 0.f, bh2 = 0.f;
    if (tid < 100) {
        hreg = ws[WS_H0 + tid];
        h_bf[tid] = f2bf(hreg);
        bh0 = b_hh[tid]; bh1 = b_hh[100 + tid]; bh2 = b_hh[200 + tid];
    } else if (tid < 128) {
        h_bf[tid] = 0;
    }
    __syncthreads();

    float* H = ws + WS_H;
    for (int t = 0; t < 60; t++) {
        // A-fragments: h_bf[kt*32 + q*8 .. +8), one b128 per k-tile (broadcast x16 lanes)
        short8 afr[4];
        #pragma unroll
        for (int kt = 0; kt < 4; kt++)
            afr[kt] = *(const short8*)&h_bf[kt * 32 + q * 8];
        #pragma unroll
        for (int i = 0; i < 4; i++) {
            f32x4 a = {0.f, 0.f, 0.f, 0.f};
            a = __builtin_amdgcn_mfma_f32_16x16x32_bf16(afr[0], bfr[i * 4 + 0], a, 0, 0, 0);
            a = __builtin_amdgcn_mfma_f32_16x16x32_bf16(afr[1], bfr[i * 4 + 1], a, 0, 0, 0);
            a = __builtin_amdgcn_mfma_f32_16x16x32_bf16(afr[2], bfr[i * 4 + 2], a, 0, 0, 0);
            a = __builtin_amdgcn_mfma_f32_16x16x32_bf16(afr[3], bfr[i * 4 + 3], a, 0, 0, 0);
            if (lane < 16) gh_lds[(wave * 4 + i) * 16 + lane] = a[0];
        }
        __syncthreads();
        if (tid < 100) {
            float gir = gi_lds[t * 300 + tid];
            float giz = gi_lds[t * 300 + 100 + tid];
            float gin = gi_lds[t * 300 + 200 + tid];
            float ghr = gh_lds[tid] + bh0;
            float ghz = gh_lds[100 + tid] + bh1;
            float ghn = gh_lds[200 + tid] + bh2;
            float r = 1.f / (1.f + __expf(-(gir + ghr)));
            float z = 1.f / (1.f + __expf(-(giz + ghz)));
            float a = fmaf(r, ghn, gin);
            float tt = __expf(-2.f * fabsf(a));
            float nn = copysignf((1.f - tt) / (1.f + tt), a);
            hreg = (1.f - z) * nn + z * hreg;
            h_bf[tid] = f2bf(hreg);
            H[t * 100 + tid] = hreg;
        }
        __syncthreads();
    }
}

// ---------------- K4: logits GEMM (bf16 MFMA) + online softmax partials ----------------
__global__ __launch_bounds__(256, 1) void k4_logits(const float* __restrict__ w_out,
                                                    const float* __restrict__ b_out,
                                                    float* __restrict__ ws) {
    const float* H = ws + WS_H;
    float* ms = ws + WS_MS;
    const int lane = threadIdx.x & 63;
    const int gw = blockIdx.x * 4 + (threadIdx.x >> 6);
    const int q = lane >> 4, n = lane & 15;
    const int k_base = q * 8;

    // A fragments: H rows (t), zero-padded to 64 x 128, float4 loads
    short8 afr[4][4];
    #pragma unroll
    for (int mt = 0; mt < 4; mt++) {
        int m = mt * 16 + n;
        #pragma unroll
        for (int kt = 0; kt < 4; kt++) {
            int k0 = kt * 32 + k_base;
            float va[8];
            #pragma unroll
            for (int jj = 0; jj < 8; jj++) va[jj] = 0.f;
            if (m < 60) {
                if (k0 + 4 <= 100) {
                    float4 a = *(const float4*)(H + m * 100 + k0);
                    va[0] = a.x; va[1] = a.y; va[2] = a.z; va[3] = a.w;
                }
                if (k0 + 8 <= 100) {
                    float4 b = *(const float4*)(H + m * 100 + k0 + 4);
                    va[4] = b.x; va[5] = b.y; va[6] = b.z; va[7] = b.w;
                }
            }
            short8 f;
            #pragma unroll
            for (int jj = 0; jj < 8; jj++) f[jj] = (short)f2bf(va[jj]);
            afr[mt][kt] = f;
        }
    }

    float mS[16], sS[16];
    #pragma unroll
    for (int i = 0; i < 16; i++) { mS[i] = -3.0e38f; sS[i] = 0.f; }

    for (int c = gw; c < NCHUNK; c += NWAVES) {
        int row = c * 16 + n;
        short8 bfr[4];
        #pragma unroll
        for (int kt = 0; kt < 4; kt++) {
            int k0 = kt * 32 + k_base;
            float va[8];
            #pragma unroll
            for (int jj = 0; jj < 8; jj++) va[jj] = 0.f;
            if (k0 + 4 <= 100) {
                float4 a = *(const float4*)(w_out + row * 100 + k0);
                va[0] = a.x; va[1] = a.y; va[2] = a.z; va[3] = a.w;
            }
            if (k0 + 8 <= 100) {
                float4 b = *(const float4*)(w_out + row * 100 + k0 + 4);
                va[4] = b.x; va[5] = b.y; va[6] = b.z; va[7] = b.w;
            }
            short8 f;
            #pragma unroll
            for (int jj = 0; jj < 8; jj++) f[jj] = (short)f2bf(va[jj]);
            bfr[kt] = f;
        }
        float bo = b_out[row];
        #pragma unroll
        for (int mt = 0; mt < 4; mt++) {
            f32x4 acc = {0.f, 0.f, 0.f, 0.f};
            acc = __builtin_amdgcn_mfma_f32_16x16x32_bf16(afr[mt][0], bfr[0], acc, 0, 0, 0);
            acc = __builtin_amdgcn_mfma_f32_16x16x32_bf16(afr[mt][1], bfr[1], acc, 0, 0, 0);
            acc = __builtin_amdgcn_mfma_f32_16x16x32_bf16(afr[mt][2], bfr[2], acc, 0, 0, 0);
            acc = __builtin_amdgcn_mfma_f32_16x16x32_bf16(afr[mt][3], bfr[3], acc, 0, 0, 0);
            #pragma unroll
            for (int reg = 0; reg < 4; reg++) {
                float x = acc[reg] + bo;            // logit for (t = mt*16+q*4+reg, v = row)
                int i = mt * 4 + reg;
                float mo = mS[i];
                float mn = fmaxf(mo, x);
                sS[i] = sS[i] * __expf(mo - mn) + __expf(x - mn);
                mS[i] = mn;
            }
        }
    }

    // reduce (m,s) across the 16 column lanes
    #pragma unroll
    for (int i = 0; i < 16; i++) {
        float m = mS[i], s = sS[i];
        #pragma unroll
        for (int off = 1; off < 16; off <<= 1) {
            float m2 = __shfl_xor(m, off);
            float s2 = __shfl_xor(s, off);
            float mn = fmaxf(m, m2);
            s = s * __expf(m - mn) + s2 * __expf(m2 - mn);
            m = mn;
        }
        mS[i] = m; sS[i] = s;
    }
    if (n == 0) {
        #pragma unroll
        for (int mt = 0; mt < 4; mt++) {
            #pragma unroll
            for (int reg = 0; reg < 4; reg++) {
                int t = mt * 16 + q * 4 + reg;
                int i = mt * 4 + reg;
                if (t < 60) {
                    float2 val; val.x = mS[i]; val.y = sS[i];
                    ((float2*)ms)[t * NWAVES + gw] = val;
                }
            }
        }
    }
}

// ---------------- K5: combine partials per t, add -logit[tok], accumulate loss ----------------
__global__ __launch_bounds__(256) void k5_final(const int* __restrict__ desc,
                                                const float* __restrict__ w_out,
                                                const float* __restrict__ b_out,
                                                const float* __restrict__ ws,
                                                float* __restrict__ out) {
    int t = blockIdx.x, tid = threadIdx.x;
    __shared__ float sm[256], ss[256], sd[256];
    const float2* ms = (const float2*)(ws + WS_MS);
    float m = -3.0e38f, s = 0.f;
    for (int i = tid; i < NWAVES; i += 256) {
        float2 p = ms[t * NWAVES + i];
        float mn = fmaxf(m, p.x);
        s = s * __expf(m - mn) + p.y * __expf(p.x - mn);
        m = mn;
    }
    sm[tid] = m; ss[tid] = s; __syncthreads();
    for (int st = 128; st > 0; st >>= 1) {
        if (tid < st) {
            float mo = sm[tid], so = ss[tid];
            float m2 = sm[tid + st], s2 = ss[tid + st];
            float mn = fmaxf(mo, m2);
            sm[tid] = mn;
            ss[tid] = so * __expf(mo - mn) + s2 * __expf(m2 - mn);
        }
        __syncthreads();
    }
    int tok = desc[t];
    float p = 0.f;
    if (tid < 100) p = ws[WS_H + t * 100 + tid] * w_out[tok * 100 + tid];
    sd[tid] = p; __syncthreads();
    for (int st = 128; st > 0; st >>= 1) {
        if (tid < st) sd[tid] += sd[tid + st];
        __syncthreads();
    }
    if (tid == 0) {
        float logit = sd[0] + b_out[tok];
        float loss = sm[0] + logf(ss[0]) - logit;
        atomicAdd(out, loss);
    }
}

extern "C" void kernel_launch(void* const* d_in, const int* in_sizes, int n_in,
                              void* d_out, int out_size, void* d_ws, size_t ws_size,
                              hipStream_t stream) {
    const int*   context = (const int*)d_in[0];
    // d_in[1] = fact_lengths (unused by reference)
    const int*   desc    = (const int*)d_in[2];
    const float* emb_ctx = (const float*)d_in[3];
    const float* emb_dec = (const float*)d_in[4];
    const float* w1      = (const float*)d_in[5];
    const float* b1      = (const float*)d_in[6];
    const float* w_ih    = (const float*)d_in[7];
    const float* w_hh    = (const float*)d_in[8];
    const float* b_ih    = (const float*)d_in[9];
    const float* b_hh    = (const float*)d_in[10];
    const float* w_out   = (const float*)d_in[11];
    const float* b_out   = (const float*)d_in[12];
    float* out = (float*)d_out;
    float* ws  = (float*)d_ws;

    k1_prep  <<<120, 128, 0, stream>>>(context, desc, emb_ctx, emb_dec, ws, out);
    k2_h0_gi <<<160, 320, 0, stream>>>(w1, b1, w_ih, b_ih, ws);
    k3_gru   <<<1,   320, 0, stream>>>(w_hh, b_hh, ws);
    k4_logits<<<256, 256, 0, stream>>>(w_out, b_out, ws);
    k5_final <<<60,  256, 0, stream>>>(desc, w_out, b_out, ws, out);
}